// Round 1
// baseline (19402.411 us; speedup 1.0000x reference)
//
#include <hip/hip_runtime.h>
#include <stdint.h>

// GRU: L=2, D=H=1024, S=512, B=32.
// Phase 1: xg[s,l,gate,b,h] = x[s,b,:] @ W[l,gate,h,:]^T  (bf16 MFMA GEMM)
// Phase 2: persistent 256-WG recurrence, U-weights LDS-resident,
//          per-(layer,b-half) 64-WG spin barriers (2 per step).

typedef __attribute__((ext_vector_type(8))) short bf16x8;
typedef __attribute__((ext_vector_type(4))) float f32x4;

#define NL 2
#define SB 32
#define HD 1024
#define SEQ 512

// ---- workspace layout (bytes) ----
#define XG_ELEMS   ((size_t)SEQ*6*SB*HD)              // 100,663,296 bf16
#define XG_OFF     0ull
#define XBF_OFF    (XG_OFF + XG_ELEMS*2)              // x as bf16
#define XBF_ELEMS  ((size_t)SEQ*SB*HD)
#define WBF_OFF    (XBF_OFF + XBF_ELEMS*2)            // W as bf16 [l*3+gate][h][d]
#define WBF_ELEMS  ((size_t)6*HD*HD)
#define HBF_OFF    (WBF_OFF + WBF_ELEMS*2)            // h bf16 [l][b][k]
#define HBF_ELEMS  ((size_t)NL*SB*HD)
#define RH_OFF     (HBF_OFF + HBF_ELEMS*2)            // r*h bf16 [l][b][k]
#define FLAGS_OFF  (RH_OFF + HBF_ELEMS*2)             // 256 u32 barrier flags
#define WS_NEED    (FLAGS_OFF + 1024ull)

__device__ __forceinline__ unsigned short f2bf(float f) {
  unsigned int u = __float_as_uint(f);
  u = u + 0x7fffu + ((u >> 16) & 1u);
  return (unsigned short)(u >> 16);
}
__device__ __forceinline__ float bf2f(unsigned int bits) {
  return __uint_as_float(bits << 16);
}
__device__ __forceinline__ f32x4 unpack4(uint2 u) {
  f32x4 v;
  v[0] = bf2f(u.x & 0xffffu); v[1] = bf2f(u.x >> 16);
  v[2] = bf2f(u.y & 0xffffu); v[3] = bf2f(u.y >> 16);
  return v;
}

// ---------------- fp32 -> bf16 convert ----------------
__global__ void cvt_f32_bf16(const float* __restrict__ src,
                             unsigned short* __restrict__ dst, int n4) {
  int i = blockIdx.x * blockDim.x + threadIdx.x;
  int st = gridDim.x * blockDim.x;
  for (; i < n4; i += st) {
    float4 v = ((const float4*)src)[i];
    ushort4 o = { f2bf(v.x), f2bf(v.y), f2bf(v.z), f2bf(v.w) };
    ((ushort4*)dst)[i] = o;
  }
}

// ---------------- phase 1 GEMM ----------------
// A = Wb[lg] : [M=1024 g][K=1024 d] row-major (k contiguous)
// Bt = xb    : [N=16384 sb][K=1024 d] row-major (k contiguous)
// C -> xg[(s*6+lg)][b][g] bf16
__global__ __launch_bounds__(256) void gemm_xg(const unsigned short* __restrict__ Wb,
                                               const unsigned short* __restrict__ xb,
                                               unsigned short* __restrict__ xg) {
  __shared__ short As[128 * 32];
  __shared__ short Bs[128 * 32];
  const int lg = blockIdx.z;
  const int m0 = blockIdx.y * 128;
  const int n0 = blockIdx.x * 128;
  const int tid = threadIdx.x, w = tid >> 6, lane = tid & 63;
  const int wm = (w >> 1) * 64, wn = (w & 1) * 64;
  const unsigned short* Ag = Wb + (size_t)lg * HD * HD;

  f32x4 acc[4][4] = {};

  for (int k0 = 0; k0 < HD; k0 += 32) {
    __syncthreads();
#pragma unroll
    for (int i = 0; i < 2; i++) {
      int off = (i * 256 + tid) * 16;      // byte offset in 8KB tile
      int rr = off >> 6;                   // row (64B per row)
      int cc = (off >> 4) & 3;             // 16B chunk in row
      *(uint4*)((char*)As + off) = *(const uint4*)(Ag + (size_t)(m0 + rr) * HD + k0 + cc * 8);
      *(uint4*)((char*)Bs + off) = *(const uint4*)(xb + (size_t)(n0 + rr) * HD + k0 + cc * 8);
    }
    __syncthreads();
    bf16x8 af[4], bf[4];
#pragma unroll
    for (int mi = 0; mi < 4; mi++)
      af[mi] = *(const bf16x8*)&As[(wm + mi * 16 + (lane & 15)) * 32 + ((lane >> 4) << 3)];
#pragma unroll
    for (int ni = 0; ni < 4; ni++)
      bf[ni] = *(const bf16x8*)&Bs[(wn + ni * 16 + (lane & 15)) * 32 + ((lane >> 4) << 3)];
#pragma unroll
    for (int mi = 0; mi < 4; mi++)
#pragma unroll
      for (int ni = 0; ni < 4; ni++)
        acc[mi][ni] = __builtin_amdgcn_mfma_f32_16x16x32_bf16(af[mi], bf[ni], acc[mi][ni], 0, 0, 0);
  }

#pragma unroll
  for (int mi = 0; mi < 4; mi++) {
    int g = m0 + wm + mi * 16 + ((lane >> 4) << 2);
#pragma unroll
    for (int ni = 0; ni < 4; ni++) {
      int n = n0 + wn + ni * 16 + (lane & 15);
      int s = n >> 5, b = n & 31;
      ushort4 o = { f2bf(acc[mi][ni][0]), f2bf(acc[mi][ni][1]),
                    f2bf(acc[mi][ni][2]), f2bf(acc[mi][ni][3]) };
      *(ushort4*)(xg + ((size_t)(s * 6 + lg)) * (SB * HD) + (size_t)b * HD + g) = o;
    }
  }
}

// ---------------- phase 2: recurrence ----------------
__device__ __forceinline__ void group_barrier(unsigned int* gf, int slot, unsigned int epoch) {
  __syncthreads();
  if (threadIdx.x == 0) {
    __builtin_amdgcn_fence(__ATOMIC_RELEASE, "agent");
    __hip_atomic_store(&gf[slot], epoch, __ATOMIC_RELAXED, __HIP_MEMORY_SCOPE_AGENT);
  }
  const int pl = threadIdx.x & 63;
  for (;;) {
    unsigned int v = __hip_atomic_load(&gf[pl], __ATOMIC_RELAXED, __HIP_MEMORY_SCOPE_AGENT);
    if (__ballot(v >= epoch) == 0xffffffffffffffffull) break;
    __builtin_amdgcn_s_sleep(1);
  }
  __builtin_amdgcn_fence(__ATOMIC_ACQUIRE, "agent");
  __syncthreads();
}

// A-fragment from swizzled LDS weights: row = lane&15, k = k0 + (lane>>4)*8
__device__ __forceinline__ bf16x8 afrag(const short* wlds, int gate, int lane, int k) {
  int r = lane & 15;
  int kk = k + ((lane >> 4) << 3);
  int ck = (kk >> 3) ^ (r & 7);            // XOR swizzle (store side matches)
  return *(const bf16x8*)&wlds[gate * 16384 + r * HD + (ck << 3)];
}

__global__ __launch_bounds__(256) void gru_rec(
    const float* __restrict__ h0,
    const float* __restrict__ Uz, const float* __restrict__ Ur, const float* __restrict__ Uh,
    const float* __restrict__ bz, const float* __restrict__ br, const float* __restrict__ bh,
    const unsigned short* __restrict__ xg,
    unsigned short* __restrict__ h_bf,
    unsigned short* __restrict__ rh_bf,
    unsigned int* __restrict__ flags,
    float* __restrict__ out) {
  __shared__ short wlds[3 * 16 * HD];   // 96 KB bf16 U-slices (forces 1 WG/CU)
  __shared__ f32x4 redv[2][256];        // 8 KB cross-wave reduction

  const int wg = blockIdx.x;            // 256 WGs
  const int l = wg >> 7;                // layer
  const int gs = wg & 63;               // g-slice id (16 rows)
  const int g0 = gs * 16;
  const int b0 = ((wg >> 6) & 1) * 16;  // b-half
  const int grp = wg >> 6;              // barrier group (l, b-half)
  const int tid = threadIdx.x;
  const int w = tid >> 6, lane = tid & 63;
  const int col = lane & 15;            // b offset within tile
  const int rb = (lane >> 4) << 2;      // g row base of C-frag
  unsigned int* gf = flags + grp * 64;

  // load U slices into LDS (bf16, XOR-swizzled chunks of 8)
  const float* Us[3] = { Uz, Ur, Uh };
#pragma unroll
  for (int gate = 0; gate < 3; gate++) {
    const float* U = Us[gate] + (size_t)l * HD * HD + (size_t)g0 * HD;
    for (int it = 0; it < 8; it++) {
      int chunk = it * 256 + tid;       // 2048 chunks of 8 elems
      int r = chunk >> 7;
      int ck = chunk & 127;
      const float* src = U + (size_t)r * HD + ck * 8;
      float4 a = *(const float4*)src;
      float4 bq = *(const float4*)(src + 4);
      bf16x8 o;
      o[0] = (short)f2bf(a.x); o[1] = (short)f2bf(a.y);
      o[2] = (short)f2bf(a.z); o[3] = (short)f2bf(a.w);
      o[4] = (short)f2bf(bq.x); o[5] = (short)f2bf(bq.y);
      o[6] = (short)f2bf(bq.z); o[7] = (short)f2bf(bq.w);
      int sck = ck ^ (r & 7);
      *(bf16x8*)&wlds[gate * 16384 + r * HD + sck * 8] = o;
    }
  }

  f32x4 vbz = *(const f32x4*)(bz + l * HD + g0 + rb);
  f32x4 vbr = *(const f32x4*)(br + l * HD + g0 + rb);
  f32x4 vbh = *(const f32x4*)(bh + l * HD + g0 + rb);

  const size_t hoff = ((size_t)(l * SB + b0 + col)) * HD;
  f32x4 hreg = *(const f32x4*)(h0 + hoff + g0 + rb);
  if (w == 0) {
    ushort4 o = { f2bf(hreg[0]), f2bf(hreg[1]), f2bf(hreg[2]), f2bf(hreg[3]) };
    *(ushort4*)(h_bf + hoff + g0 + rb) = o;
  }
  unsigned int epoch = 1;
  group_barrier(gf, gs, epoch);

  const int kb = w * 256;               // per-wave K chunk

  for (int s = 0; s < SEQ; s++) {
    size_t xbase = ((size_t)s * 6 + l * 3) * (SB * HD) + (size_t)(b0 + col) * HD + g0 + rb;
    uint2 xz2 = *(const uint2*)(xg + xbase);
    uint2 xr2 = *(const uint2*)(xg + xbase + SB * HD);
    uint2 xh2 = *(const uint2*)(xg + xbase + 2 * SB * HD);

    // ---- phase A: z, r ----
    f32x4 accz = { 0, 0, 0, 0 }, accr = { 0, 0, 0, 0 };
#pragma unroll
    for (int kk = 0; kk < 256; kk += 32) {
      int k = kb + kk;
      bf16x8 hf = *(const bf16x8*)(h_bf + hoff + k + ((lane >> 4) << 3));
      bf16x8 az = afrag(wlds, 0, lane, k);
      bf16x8 ar = afrag(wlds, 1, lane, k);
      accz = __builtin_amdgcn_mfma_f32_16x16x32_bf16(az, hf, accz, 0, 0, 0);
      accr = __builtin_amdgcn_mfma_f32_16x16x32_bf16(ar, hf, accr, 0, 0, 0);
    }
    redv[0][w * 64 + lane] = accz;
    redv[1][w * 64 + lane] = accr;
    __syncthreads();
    f32x4 sz = redv[0][lane] + redv[0][64 + lane] + redv[0][128 + lane] + redv[0][192 + lane];
    f32x4 sr = redv[1][lane] + redv[1][64 + lane] + redv[1][128 + lane] + redv[1][192 + lane];

    f32x4 xzf = unpack4(xz2), xrf = unpack4(xr2);
    f32x4 z, r;
#pragma unroll
    for (int j = 0; j < 4; j++) {
      float za = xzf[j] + vbz[j] + sz[j];
      float ra = xrf[j] + vbr[j] + sr[j];
      z[j] = 1.f / (1.f + __expf(-za));
      r[j] = 1.f / (1.f + __expf(-ra));
    }
    if (w == 0) {
      ushort4 o = { f2bf(r[0] * hreg[0]), f2bf(r[1] * hreg[1]),
                    f2bf(r[2] * hreg[2]), f2bf(r[3] * hreg[3]) };
      *(ushort4*)(rh_bf + hoff + g0 + rb) = o;
    }
    epoch++;
    group_barrier(gf, gs, epoch);

    // ---- phase B: hh, h update ----
    f32x4 acch = { 0, 0, 0, 0 };
#pragma unroll
    for (int kk = 0; kk < 256; kk += 32) {
      int k = kb + kk;
      bf16x8 rf = *(const bf16x8*)(rh_bf + hoff + k + ((lane >> 4) << 3));
      bf16x8 ah = afrag(wlds, 2, lane, k);
      acch = __builtin_amdgcn_mfma_f32_16x16x32_bf16(ah, rf, acch, 0, 0, 0);
    }
    redv[0][w * 64 + lane] = acch;
    __syncthreads();
    f32x4 sh = redv[0][lane] + redv[0][64 + lane] + redv[0][128 + lane] + redv[0][192 + lane];

    f32x4 xhf = unpack4(xh2);
#pragma unroll
    for (int j = 0; j < 4; j++) {
      float ha = xhf[j] + vbh[j] + sh[j];
      float hh = tanhf(ha);
      hreg[j] = (1.f - z[j]) * hreg[j] + z[j] * hh;
    }
    if (w == 0) {
      ushort4 o = { f2bf(hreg[0]), f2bf(hreg[1]), f2bf(hreg[2]), f2bf(hreg[3]) };
      *(ushort4*)(h_bf + hoff + g0 + rb) = o;
      if (l == 1)
        *(f32x4*)(out + (size_t)s * (SB * HD) + (size_t)(b0 + col) * HD + g0 + rb) = hreg;
      if (s == SEQ - 1)
        *(f32x4*)(out + (size_t)SEQ * SB * HD + hoff + g0 + rb) = hreg;
    }
    epoch++;
    group_barrier(gf, gs, epoch);
  }
}

extern "C" void kernel_launch(void* const* d_in, const int* in_sizes, int n_in,
                              void* d_out, int out_size, void* d_ws, size_t ws_size,
                              hipStream_t stream) {
  const float* x  = (const float*)d_in[0];
  const float* h0 = (const float*)d_in[1];
  const float* Wz = (const float*)d_in[2];
  const float* Wr = (const float*)d_in[3];
  const float* Wh = (const float*)d_in[4];
  const float* Uz = (const float*)d_in[5];
  const float* Ur = (const float*)d_in[6];
  const float* Uh = (const float*)d_in[7];
  const float* bz = (const float*)d_in[8];
  const float* br = (const float*)d_in[9];
  const float* bh = (const float*)d_in[10];

  char* ws = (char*)d_ws;
  unsigned short* xg    = (unsigned short*)(ws + XG_OFF);
  unsigned short* xbf   = (unsigned short*)(ws + XBF_OFF);
  unsigned short* wbf   = (unsigned short*)(ws + WBF_OFF);
  unsigned short* hbf   = (unsigned short*)(ws + HBF_OFF);
  unsigned short* rhbf  = (unsigned short*)(ws + RH_OFF);
  unsigned int*   flags = (unsigned int*)(ws + FLAGS_OFF);

  hipMemsetAsync(flags, 0, 256 * sizeof(unsigned int), stream);

  cvt_f32_bf16<<<1024, 256, 0, stream>>>(x, xbf, (int)(XBF_ELEMS / 4));
  const float* Wsrc[3] = { Wz, Wr, Wh };
  for (int gate = 0; gate < 3; gate++)
    for (int l = 0; l < 2; l++)
      cvt_f32_bf16<<<512, 256, 0, stream>>>(Wsrc[gate] + (size_t)l * HD * HD,
                                            wbf + ((size_t)(l * 3 + gate)) * HD * HD,
                                            HD * HD / 4);

  gemm_xg<<<dim3(128, 8, 6), 256, 0, stream>>>(wbf, xbf, xg);

  gru_rec<<<256, 256, 0, stream>>>(h0, Uz, Ur, Uh, bz, br, bh,
                                   xg, hbf, rhbf, flags, (float*)d_out);
}

// Round 2
// 4828.375 us; speedup vs baseline: 4.0184x; 4.0184x over previous
//
#include <hip/hip_runtime.h>
#include <stdint.h>

// GRU: L=2, D=H=1024, S=512, B=32.
// Phase 1: xg[s,l,gate,b,h] = x[s,b,:] @ W[l,gate,h,:]^T  (bf16 MFMA GEMM)
// Phase 2: persistent 256-WG recurrence, U-weights LDS-resident.
//   Cross-WG sync: NO agent fences (no buffer_wbl2/buffer_inv). All shared
//   state (h, r*h) moves via agent-scope relaxed atomics (sc1 write-through);
//   producer does s_waitcnt vmcnt(0) then relaxed atomicAdd on a per-group
//   counter; wave 0 polls the counter, __syncthreads releases the WG.

typedef __attribute__((ext_vector_type(8))) short bf16x8;
typedef __attribute__((ext_vector_type(4))) float f32x4;

#define NL 2
#define SB 32
#define HD 1024
#define SEQ 512

// ---- workspace layout (bytes) ----
#define XG_ELEMS   ((size_t)SEQ*6*SB*HD)
#define XG_OFF     0ull
#define XBF_OFF    (XG_OFF + XG_ELEMS*2)
#define XBF_ELEMS  ((size_t)SEQ*SB*HD)
#define WBF_OFF    (XBF_OFF + XBF_ELEMS*2)
#define WBF_ELEMS  ((size_t)6*HD*HD)
#define HBF_OFF    (WBF_OFF + WBF_ELEMS*2)
#define HBF_ELEMS  ((size_t)NL*SB*HD)
#define RH_OFF     (HBF_OFF + HBF_ELEMS*2)
#define FLAGS_OFF  (RH_OFF + HBF_ELEMS*2)
#define WS_NEED    (FLAGS_OFF + 1024ull)

__device__ __forceinline__ unsigned short f2bf(float f) {
  unsigned int u = __float_as_uint(f);
  u = u + 0x7fffu + ((u >> 16) & 1u);
  return (unsigned short)(u >> 16);
}
__device__ __forceinline__ float bf2f(unsigned int bits) {
  return __uint_as_float(bits << 16);
}
__device__ __forceinline__ f32x4 unpack4(uint2 u) {
  f32x4 v;
  v[0] = bf2f(u.x & 0xffffu); v[1] = bf2f(u.x >> 16);
  v[2] = bf2f(u.y & 0xffffu); v[3] = bf2f(u.y >> 16);
  return v;
}

// write-through (coherence-point) 8B atomic load/store, agent scope, relaxed
__device__ __forceinline__ unsigned long long ld_wt(const void* p) {
  return __hip_atomic_load((unsigned long long*)p, __ATOMIC_RELAXED,
                           __HIP_MEMORY_SCOPE_AGENT);
}
__device__ __forceinline__ void st_wt(void* p, unsigned long long v) {
  __hip_atomic_store((unsigned long long*)p, v, __ATOMIC_RELAXED,
                     __HIP_MEMORY_SCOPE_AGENT);
}

// ---------------- fp32 -> bf16 convert ----------------
__global__ void cvt_f32_bf16(const float* __restrict__ src,
                             unsigned short* __restrict__ dst, int n4) {
  int i = blockIdx.x * blockDim.x + threadIdx.x;
  int st = gridDim.x * blockDim.x;
  for (; i < n4; i += st) {
    float4 v = ((const float4*)src)[i];
    ushort4 o = { f2bf(v.x), f2bf(v.y), f2bf(v.z), f2bf(v.w) };
    ((ushort4*)dst)[i] = o;
  }
}

// ---------------- phase 1 GEMM ----------------
__global__ __launch_bounds__(256) void gemm_xg(const unsigned short* __restrict__ Wb,
                                               const unsigned short* __restrict__ xb,
                                               unsigned short* __restrict__ xg) {
  __shared__ short As[128 * 32];
  __shared__ short Bs[128 * 32];
  const int lg = blockIdx.z;
  const int m0 = blockIdx.y * 128;
  const int n0 = blockIdx.x * 128;
  const int tid = threadIdx.x, w = tid >> 6, lane = tid & 63;
  const int wm = (w >> 1) * 64, wn = (w & 1) * 64;
  const unsigned short* Ag = Wb + (size_t)lg * HD * HD;

  f32x4 acc[4][4] = {};

  for (int k0 = 0; k0 < HD; k0 += 32) {
    __syncthreads();
#pragma unroll
    for (int i = 0; i < 2; i++) {
      int off = (i * 256 + tid) * 16;
      int rr = off >> 6;
      int cc = (off >> 4) & 3;
      *(uint4*)((char*)As + off) = *(const uint4*)(Ag + (size_t)(m0 + rr) * HD + k0 + cc * 8);
      *(uint4*)((char*)Bs + off) = *(const uint4*)(xb + (size_t)(n0 + rr) * HD + k0 + cc * 8);
    }
    __syncthreads();
    bf16x8 af[4], bf[4];
#pragma unroll
    for (int mi = 0; mi < 4; mi++)
      af[mi] = *(const bf16x8*)&As[(wm + mi * 16 + (lane & 15)) * 32 + ((lane >> 4) << 3)];
#pragma unroll
    for (int ni = 0; ni < 4; ni++)
      bf[ni] = *(const bf16x8*)&Bs[(wn + ni * 16 + (lane & 15)) * 32 + ((lane >> 4) << 3)];
#pragma unroll
    for (int mi = 0; mi < 4; mi++)
#pragma unroll
      for (int ni = 0; ni < 4; ni++)
        acc[mi][ni] = __builtin_amdgcn_mfma_f32_16x16x32_bf16(af[mi], bf[ni], acc[mi][ni], 0, 0, 0);
  }

#pragma unroll
  for (int mi = 0; mi < 4; mi++) {
    int g = m0 + wm + mi * 16 + ((lane >> 4) << 2);
#pragma unroll
    for (int ni = 0; ni < 4; ni++) {
      int n = n0 + wn + ni * 16 + (lane & 15);
      int s = n >> 5, b = n & 31;
      ushort4 o = { f2bf(acc[mi][ni][0]), f2bf(acc[mi][ni][1]),
                    f2bf(acc[mi][ni][2]), f2bf(acc[mi][ni][3]) };
      *(ushort4*)(xg + ((size_t)(s * 6 + lg)) * (SB * HD) + (size_t)b * HD + g) = o;
    }
  }
}

// ---------------- phase 2: recurrence ----------------
// Barrier: counter-based, monotonic target, no fences. Producer stores are
// write-through atomics; vmcnt(0) retirement => visible at coherence point.
__device__ __forceinline__ void group_barrier(unsigned int* cnt, unsigned int tgt) {
  __syncthreads();
  asm volatile("s_waitcnt vmcnt(0)" ::: "memory");
  if (threadIdx.x == 0)
    __hip_atomic_fetch_add(cnt, 1u, __ATOMIC_RELAXED, __HIP_MEMORY_SCOPE_AGENT);
  if (threadIdx.x < 64) {
    while (__hip_atomic_load(cnt, __ATOMIC_RELAXED, __HIP_MEMORY_SCOPE_AGENT) < tgt)
      __builtin_amdgcn_s_sleep(1);
  }
  __syncthreads();
}

__device__ __forceinline__ bf16x8 afrag(const short* wlds, int gate, int lane, int k) {
  int r = lane & 15;
  int kk = k + ((lane >> 4) << 3);
  int ck = (kk >> 3) ^ (r & 7);
  return *(const bf16x8*)&wlds[gate * 16384 + r * HD + (ck << 3)];
}

__global__ __launch_bounds__(256) void gru_rec(
    const float* __restrict__ h0,
    const float* __restrict__ Uz, const float* __restrict__ Ur, const float* __restrict__ Uh,
    const float* __restrict__ bz, const float* __restrict__ br, const float* __restrict__ bh,
    const unsigned short* __restrict__ xg,
    unsigned short* __restrict__ h_bf,
    unsigned short* __restrict__ rh_bf,
    unsigned int* __restrict__ flags,
    float* __restrict__ out) {
  __shared__ short wlds[3 * 16 * HD];   // 96 KB bf16 U-slices (1 WG/CU)
  __shared__ f32x4 redv[2][256];        // 8 KB cross-wave reduction

  const int wg = blockIdx.x;
  const int l = wg >> 7;
  const int gs = wg & 63;
  const int g0 = gs * 16;
  const int b0 = ((wg >> 6) & 1) * 16;
  const int grp = wg >> 6;
  const int tid = threadIdx.x;
  const int w = tid >> 6, lane = tid & 63;
  const int col = lane & 15;
  const int rb = (lane >> 4) << 2;
  unsigned int* cnt = flags + grp * 64;   // groups 256B apart

  // load U slices into LDS (bf16, XOR-swizzled chunks of 8)
  const float* Us[3] = { Uz, Ur, Uh };
#pragma unroll
  for (int gate = 0; gate < 3; gate++) {
    const float* U = Us[gate] + (size_t)l * HD * HD + (size_t)g0 * HD;
    for (int it = 0; it < 8; it++) {
      int chunk = it * 256 + tid;
      int r = chunk >> 7;
      int ck = chunk & 127;
      const float* src = U + (size_t)r * HD + ck * 8;
      float4 a = *(const float4*)src;
      float4 bq = *(const float4*)(src + 4);
      bf16x8 o;
      o[0] = (short)f2bf(a.x); o[1] = (short)f2bf(a.y);
      o[2] = (short)f2bf(a.z); o[3] = (short)f2bf(a.w);
      o[4] = (short)f2bf(bq.x); o[5] = (short)f2bf(bq.y);
      o[6] = (short)f2bf(bq.z); o[7] = (short)f2bf(bq.w);
      int sck = ck ^ (r & 7);
      *(bf16x8*)&wlds[gate * 16384 + r * HD + sck * 8] = o;
    }
  }

  f32x4 vbz = *(const f32x4*)(bz + l * HD + g0 + rb);
  f32x4 vbr = *(const f32x4*)(br + l * HD + g0 + rb);
  f32x4 vbh = *(const f32x4*)(bh + l * HD + g0 + rb);

  const size_t hoff = ((size_t)(l * SB + b0 + col)) * HD;
  f32x4 hreg = *(const f32x4*)(h0 + hoff + g0 + rb);

  unsigned int tgt = 64;
  if (w == 0) {
    ushort4 o = { f2bf(hreg[0]), f2bf(hreg[1]), f2bf(hreg[2]), f2bf(hreg[3]) };
    unsigned long long v; __builtin_memcpy(&v, &o, 8);
    st_wt(h_bf + hoff + g0 + rb, v);
  }
  group_barrier(cnt, tgt); tgt += 64;

  const int kb = w * 256;
  const unsigned long long* hq =
      (const unsigned long long*)(h_bf + hoff + kb + ((lane >> 4) << 3));
  const unsigned long long* rq =
      (const unsigned long long*)(rh_bf + hoff + kb + ((lane >> 4) << 3));

  for (int s = 0; s < SEQ; s++) {
    uint2 xz2 = {}, xr2 = {}, xh2 = {};
    if (w == 0) {
      size_t xbase = ((size_t)s * 6 + l * 3) * (SB * HD) + (size_t)(b0 + col) * HD + g0 + rb;
      xz2 = *(const uint2*)(xg + xbase);
      xr2 = *(const uint2*)(xg + xbase + SB * HD);
      xh2 = *(const uint2*)(xg + xbase + 2 * SB * HD);
    }

    // ---- phase A: z, r ----
    unsigned long long ha[16];
#pragma unroll
    for (int i = 0; i < 8; i++) {
      ha[2 * i]     = ld_wt(hq + i * 8);
      ha[2 * i + 1] = ld_wt(hq + i * 8 + 1);
    }
    f32x4 accz = { 0, 0, 0, 0 }, accr = { 0, 0, 0, 0 };
#pragma unroll
    for (int i = 0; i < 8; i++) {
      int k = kb + i * 32;
      union { unsigned long long q[2]; bf16x8 v; } u;
      u.q[0] = ha[2 * i]; u.q[1] = ha[2 * i + 1];
      bf16x8 az = afrag(wlds, 0, lane, k);
      bf16x8 ar = afrag(wlds, 1, lane, k);
      accz = __builtin_amdgcn_mfma_f32_16x16x32_bf16(az, u.v, accz, 0, 0, 0);
      accr = __builtin_amdgcn_mfma_f32_16x16x32_bf16(ar, u.v, accr, 0, 0, 0);
    }
    redv[0][w * 64 + lane] = accz;
    redv[1][w * 64 + lane] = accr;
    __syncthreads();

    f32x4 z = { 0, 0, 0, 0 };
    if (w == 0) {
      f32x4 sz = redv[0][lane] + redv[0][64 + lane] + redv[0][128 + lane] + redv[0][192 + lane];
      f32x4 sr = redv[1][lane] + redv[1][64 + lane] + redv[1][128 + lane] + redv[1][192 + lane];
      f32x4 xzf = unpack4(xz2), xrf = unpack4(xr2);
      f32x4 r;
#pragma unroll
      for (int j = 0; j < 4; j++) {
        float za = xzf[j] + vbz[j] + sz[j];
        float ra = xrf[j] + vbr[j] + sr[j];
        z[j] = 1.f / (1.f + __expf(-za));
        r[j] = 1.f / (1.f + __expf(-ra));
      }
      ushort4 o = { f2bf(r[0] * hreg[0]), f2bf(r[1] * hreg[1]),
                    f2bf(r[2] * hreg[2]), f2bf(r[3] * hreg[3]) };
      unsigned long long v; __builtin_memcpy(&v, &o, 8);
      st_wt(rh_bf + hoff + g0 + rb, v);
    }
    group_barrier(cnt, tgt); tgt += 64;

    // ---- phase B: hh, h update ----
    unsigned long long ra[16];
#pragma unroll
    for (int i = 0; i < 8; i++) {
      ra[2 * i]     = ld_wt(rq + i * 8);
      ra[2 * i + 1] = ld_wt(rq + i * 8 + 1);
    }
    f32x4 acch = { 0, 0, 0, 0 };
#pragma unroll
    for (int i = 0; i < 8; i++) {
      int k = kb + i * 32;
      union { unsigned long long q[2]; bf16x8 v; } u;
      u.q[0] = ra[2 * i]; u.q[1] = ra[2 * i + 1];
      bf16x8 ah = afrag(wlds, 2, lane, k);
      acch = __builtin_amdgcn_mfma_f32_16x16x32_bf16(ah, u.v, acch, 0, 0, 0);
    }
    redv[0][w * 64 + lane] = acch;
    __syncthreads();

    if (w == 0) {
      f32x4 sh = redv[0][lane] + redv[0][64 + lane] + redv[0][128 + lane] + redv[0][192 + lane];
      f32x4 xhf = unpack4(xh2);
#pragma unroll
      for (int j = 0; j < 4; j++) {
        float ha2 = xhf[j] + vbh[j] + sh[j];
        float hh = tanhf(ha2);
        hreg[j] = (1.f - z[j]) * hreg[j] + z[j] * hh;
      }
      ushort4 o = { f2bf(hreg[0]), f2bf(hreg[1]), f2bf(hreg[2]), f2bf(hreg[3]) };
      unsigned long long v; __builtin_memcpy(&v, &o, 8);
      st_wt(h_bf + hoff + g0 + rb, v);
      if (l == 1)
        *(f32x4*)(out + (size_t)s * (SB * HD) + (size_t)(b0 + col) * HD + g0 + rb) = hreg;
      if (s == SEQ - 1)
        *(f32x4*)(out + (size_t)SEQ * SB * HD + hoff + g0 + rb) = hreg;
    }
    group_barrier(cnt, tgt); tgt += 64;
  }
}

extern "C" void kernel_launch(void* const* d_in, const int* in_sizes, int n_in,
                              void* d_out, int out_size, void* d_ws, size_t ws_size,
                              hipStream_t stream) {
  const float* x  = (const float*)d_in[0];
  const float* h0 = (const float*)d_in[1];
  const float* Wz = (const float*)d_in[2];
  const float* Wr = (const float*)d_in[3];
  const float* Wh = (const float*)d_in[4];
  const float* Uz = (const float*)d_in[5];
  const float* Ur = (const float*)d_in[6];
  const float* Uh = (const float*)d_in[7];
  const float* bz = (const float*)d_in[8];
  const float* br = (const float*)d_in[9];
  const float* bh = (const float*)d_in[10];

  char* ws = (char*)d_ws;
  unsigned short* xg    = (unsigned short*)(ws + XG_OFF);
  unsigned short* xbf   = (unsigned short*)(ws + XBF_OFF);
  unsigned short* wbf   = (unsigned short*)(ws + WBF_OFF);
  unsigned short* hbf   = (unsigned short*)(ws + HBF_OFF);
  unsigned short* rhbf  = (unsigned short*)(ws + RH_OFF);
  unsigned int*   flags = (unsigned int*)(ws + FLAGS_OFF);

  hipMemsetAsync(flags, 0, 256 * sizeof(unsigned int), stream);

  cvt_f32_bf16<<<1024, 256, 0, stream>>>(x, xbf, (int)(XBF_ELEMS / 4));
  const float* Wsrc[3] = { Wz, Wr, Wh };
  for (int gate = 0; gate < 3; gate++)
    for (int l = 0; l < 2; l++)
      cvt_f32_bf16<<<512, 256, 0, stream>>>(Wsrc[gate] + (size_t)l * HD * HD,
                                            wbf + ((size_t)(l * 3 + gate)) * HD * HD,
                                            HD * HD / 4);

  gemm_xg<<<dim3(128, 8, 6), 256, 0, stream>>>(wbf, xbf, xg);

  gru_rec<<<256, 256, 0, stream>>>(h0, Uz, Ur, Uh, bz, br, bh,
                                   xg, hbf, rhbf, flags, (float*)d_out);
}